// Round 1
// baseline (261.109 us; speedup 1.0000x reference)
//
#include <hip/hip_runtime.h>
#include <stdint.h>

#define DEV __device__ __forceinline__

typedef short bf16x8 __attribute__((ext_vector_type(8)));
typedef float f32x4 __attribute__((ext_vector_type(4)));

DEV short f2bf(float f) {
  uint32_t x = __builtin_bit_cast(uint32_t, f);
  uint32_t r = x + 0x7fffu + ((x >> 16) & 1u);
  return (short)(r >> 16);
}

// ---------------- fp32 -> bf16 convert (8 elems/thread) ----------------
__global__ __launch_bounds__(256) void k_cvt(const float* __restrict__ in,
                                             short* __restrict__ out, int n8) {
  int i = blockIdx.x * 256 + threadIdx.x;
  if (i >= n8) return;
  const float4* p = (const float4*)in + (size_t)i * 2;
  float4 a = p[0], b = p[1];
  bf16x8 v;
  v[0] = f2bf(a.x); v[1] = f2bf(a.y); v[2] = f2bf(a.z); v[3] = f2bf(a.w);
  v[4] = f2bf(b.x); v[5] = f2bf(b.y); v[6] = f2bf(b.z); v[7] = f2bf(b.w);
  *(bf16x8*)(out + (size_t)i * 8) = v;
}

// ------------- transpose + convert: in[K][N] f32 -> out[N][K] bf16 -------------
__global__ __launch_bounds__(256) void k_tcvt(const float* __restrict__ in,
                                              short* __restrict__ out, int K, int N) {
  __shared__ float tile[64][65];
  int t = threadIdx.x;
  int n0 = blockIdx.x * 64, k0 = blockIdx.y * 64;
  int kl = t >> 4, nl = (t & 15) * 4;
#pragma unroll
  for (int it = 0; it < 4; ++it) {
    float4 v = *(const float4*)&in[(size_t)(k0 + kl + it * 16) * N + n0 + nl];
    tile[nl + 0][kl + it * 16] = v.x;
    tile[nl + 1][kl + it * 16] = v.y;
    tile[nl + 2][kl + it * 16] = v.z;
    tile[nl + 3][kl + it * 16] = v.w;
  }
  __syncthreads();
  int no = t >> 2, kc = (t & 3) * 16;
  bf16x8 v0, v1;
#pragma unroll
  for (int c = 0; c < 8; ++c) v0[c] = f2bf(tile[no][kc + c]);
#pragma unroll
  for (int c = 0; c < 8; ++c) v1[c] = f2bf(tile[no][kc + 8 + c]);
  size_t ob = (size_t)(n0 + no) * K + k0 + kc;
  *(bf16x8*)&out[ob] = v0;
  *(bf16x8*)&out[ob + 8] = v1;
}

// ------------- per-head V transpose: v[bh][1024][64] -> vt[bh][64][1024] (bf16) -------------
__global__ __launch_bounds__(256) void k_vt(const short* __restrict__ vin,
                                            short* __restrict__ vt) {
  __shared__ alignas(16) short tile[64][72];
  int t = threadIdx.x;
  int sc = blockIdx.x, bh = blockIdx.y;
  int sl = t >> 3, dc = (t & 7) * 8;
  const short* base = vin + ((size_t)bh * 1024 + sc * 64) * 64;
#pragma unroll
  for (int it = 0; it < 2; ++it)
    *(bf16x8*)&tile[sl + it * 32][dc] = *(const bf16x8*)&base[(size_t)(sl + it * 32) * 64 + dc];
  __syncthreads();
  int d = t >> 2, s2 = (t & 3) * 16;
  bf16x8 v0, v1;
#pragma unroll
  for (int c = 0; c < 8; ++c) v0[c] = tile[s2 + c][d];
#pragma unroll
  for (int c = 0; c < 8; ++c) v1[c] = tile[s2 + 8 + c][d];
  size_t ob = (size_t)bh * 65536 + (size_t)d * 1024 + sc * 64 + s2;
  *(bf16x8*)&vt[ob] = v0;
  *(bf16x8*)&vt[ob + 8] = v1;
}

// ------------- GEMM: A[M][1024] bf16 (K-major), Bw[N][1024] bf16 (B^T, K-major) -------------
// MODE 0: QKV -> q/k/v buffers [bh][s][64] bf16 (+bias). MODE 1: proj -> f32 out (+bias).
template <int MODE>
__global__ __launch_bounds__(256) void k_gemm(const short* __restrict__ A,
                                              const short* __restrict__ Bw,
                                              const float* __restrict__ bias,
                                              void* o0, void* o1, void* o2) {
  __shared__ alignas(16) short lA[128 * 72];
  __shared__ alignas(16) short lB[128 * 72];
  int t = threadIdx.x;
  int w = t >> 6, l = t & 63;
  int wr = w >> 1, wc = w & 1;
  int lr = l & 15, lg = l >> 4;
  int m0 = blockIdx.y * 128, n0 = blockIdx.x * 128;
  f32x4 acc[4][4] = {};
  int srow = t >> 3, sch = (t & 7) * 8;
  const short* ap = A + (size_t)(m0 + srow) * 1024 + sch;
  const short* bp = Bw + (size_t)(n0 + srow) * 1024 + sch;

  for (int k0 = 0; k0 < 1024; k0 += 64) {
    bf16x8 ra[4], rb[4];
#pragma unroll
    for (int it = 0; it < 4; ++it) {
      ra[it] = *(const bf16x8*)(ap + (size_t)it * 32 * 1024 + k0);
      rb[it] = *(const bf16x8*)(bp + (size_t)it * 32 * 1024 + k0);
    }
    __syncthreads();
#pragma unroll
    for (int it = 0; it < 4; ++it) {
      *(bf16x8*)&lA[(srow + it * 32) * 72 + sch] = ra[it];
      *(bf16x8*)&lB[(srow + it * 32) * 72 + sch] = rb[it];
    }
    __syncthreads();
    bf16x8 af[4][2], bfr[4][2];
#pragma unroll
    for (int i = 0; i < 4; ++i)
#pragma unroll
      for (int kh = 0; kh < 2; ++kh) {
        af[i][kh] = *(const bf16x8*)&lA[(wr * 64 + i * 16 + lr) * 72 + kh * 32 + lg * 8];
        bfr[i][kh] = *(const bf16x8*)&lB[(wc * 64 + i * 16 + lr) * 72 + kh * 32 + lg * 8];
      }
#pragma unroll
    for (int i = 0; i < 4; ++i)
#pragma unroll
      for (int j = 0; j < 4; ++j)
#pragma unroll
        for (int kh = 0; kh < 2; ++kh)
          acc[i][j] = __builtin_amdgcn_mfma_f32_16x16x32_bf16(af[i][kh], bfr[j][kh], acc[i][j], 0, 0, 0);
  }

  if (MODE == 0) {
    short* outs[3] = {(short*)o0, (short*)o1, (short*)o2};
    short* op = outs[n0 >> 10];
#pragma unroll
    for (int i = 0; i < 4; ++i)
#pragma unroll
      for (int j = 0; j < 4; ++j)
#pragma unroll
        for (int r = 0; r < 4; ++r) {
          int mm = m0 + wr * 64 + i * 16 + lg * 4 + r;
          int nn = n0 + wc * 64 + j * 16 + lr;
          float val = acc[i][j][r] + bias[nn];
          int hh = (nn >> 6) & 15, dd = nn & 63;
          int bb = mm >> 10, ss = mm & 1023;
          op[((size_t)(bb * 16 + hh) * 1024 + ss) * 64 + dd] = f2bf(val);
        }
  } else {
    float* op = (float*)o0;
#pragma unroll
    for (int i = 0; i < 4; ++i)
#pragma unroll
      for (int j = 0; j < 4; ++j)
#pragma unroll
        for (int r = 0; r < 4; ++r) {
          int mm = m0 + wr * 64 + i * 16 + lg * 4 + r;
          int nn = n0 + wc * 64 + j * 16 + lr;
          op[(size_t)mm * 1024 + nn] = acc[i][j][r] + bias[nn];
        }
  }
}

// ------------- flash attention: qb/kb [bh][s][64], vt [bh][64][1024] -> ao [tok][1024] bf16 -------------
__global__ __launch_bounds__(256) void k_attn(const short* __restrict__ qb,
                                              const short* __restrict__ kb,
                                              const short* __restrict__ vt,
                                              short* __restrict__ ao) {
  __shared__ alignas(16) short lK[64 * 72];
  __shared__ alignas(16) short lV[64 * 72];
  __shared__ alignas(16) short lP[4][16 * 72];
  int t = threadIdx.x, w = t >> 6, l = t & 63;
  int lr = l & 15, lg = l >> 4;
  int bh = blockIdx.x >> 4, qt = blockIdx.x & 15;

  int qrow = qt * 64 + w * 16 + lr;
  const short* qp = qb + ((size_t)bh * 1024 + qrow) * 64 + lg * 8;
  bf16x8 qf0 = *(const bf16x8*)qp;
  bf16x8 qf1 = *(const bf16x8*)(qp + 32);

  const short* kbase = kb + (size_t)bh * 65536;
  const short* vbase = vt + (size_t)bh * 65536;

  f32x4 acc[4] = {};
  float m2[4], ls[4];
#pragma unroll
  for (int r = 0; r < 4; ++r) { m2[r] = -3.0e38f; ls[r] = 0.f; }
  const float C = 0.125f * 1.44269504088896f;  // scale * log2(e)
  int srow = t >> 3, sch = (t & 7) * 8;

  for (int kv0 = 0; kv0 < 1024; kv0 += 64) {
    bf16x8 rk[2], rv[2];
#pragma unroll
    for (int it = 0; it < 2; ++it) {
      rk[it] = *(const bf16x8*)&kbase[(size_t)(kv0 + srow + it * 32) * 64 + sch];
      rv[it] = *(const bf16x8*)&vbase[(size_t)(srow + it * 32) * 1024 + kv0 + sch];
    }
    __syncthreads();
#pragma unroll
    for (int it = 0; it < 2; ++it) {
      *(bf16x8*)&lK[(srow + it * 32) * 72 + sch] = rk[it];
      *(bf16x8*)&lV[(srow + it * 32) * 72 + sch] = rv[it];
    }
    __syncthreads();

    // S = Q K^T (16q x 64kv per wave), in exp2 domain
    f32x4 s[4];
#pragma unroll
    for (int tt = 0; tt < 4; ++tt) {
      bf16x8 kf0 = *(const bf16x8*)&lK[(tt * 16 + lr) * 72 + lg * 8];
      bf16x8 kf1 = *(const bf16x8*)&lK[(tt * 16 + lr) * 72 + 32 + lg * 8];
      f32x4 z = {};
      z = __builtin_amdgcn_mfma_f32_16x16x32_bf16(qf0, kf0, z, 0, 0, 0);
      z = __builtin_amdgcn_mfma_f32_16x16x32_bf16(qf1, kf1, z, 0, 0, 0);
      s[tt] = z * C;
    }

    // online softmax: row stats across 16 lanes (cols) + 4 subtiles
    float mx[4], al[4];
#pragma unroll
    for (int r = 0; r < 4; ++r)
      mx[r] = fmaxf(fmaxf(s[0][r], s[1][r]), fmaxf(s[2][r], s[3][r]));
#pragma unroll
    for (int d = 1; d < 16; d <<= 1)
#pragma unroll
      for (int r = 0; r < 4; ++r)
        mx[r] = fmaxf(mx[r], __shfl_xor(mx[r], d));
#pragma unroll
    for (int r = 0; r < 4; ++r) {
      float mn = fmaxf(m2[r], mx[r]);
      al[r] = __builtin_exp2f(m2[r] - mn);
      m2[r] = mn;
    }
    float rs[4] = {0.f, 0.f, 0.f, 0.f};
#pragma unroll
    for (int tt = 0; tt < 4; ++tt)
#pragma unroll
      for (int r = 0; r < 4; ++r) {
        float p = __builtin_exp2f(s[tt][r] - m2[r]);
        s[tt][r] = p;
        rs[r] += p;
      }
#pragma unroll
    for (int d = 1; d < 16; d <<= 1)
#pragma unroll
      for (int r = 0; r < 4; ++r)
        rs[r] += __shfl_xor(rs[r], d);
#pragma unroll
    for (int r = 0; r < 4; ++r) ls[r] = ls[r] * al[r] + rs[r];
#pragma unroll
    for (int j = 0; j < 4; ++j)
#pragma unroll
      for (int r = 0; r < 4; ++r)
        acc[j][r] *= al[r];

    // P through per-wave private LDS to get A-fragment layout (no barrier: same wave)
    short* pw = &lP[w][0];
#pragma unroll
    for (int tt = 0; tt < 4; ++tt)
#pragma unroll
      for (int r = 0; r < 4; ++r)
        pw[(lg * 4 + r) * 72 + tt * 16 + lr] = f2bf(s[tt][r]);
    bf16x8 pa0 = *(const bf16x8*)&pw[lr * 72 + lg * 8];
    bf16x8 pa1 = *(const bf16x8*)&pw[lr * 72 + 32 + lg * 8];

    // O += P V
#pragma unroll
    for (int j = 0; j < 4; ++j) {
      bf16x8 vf0 = *(const bf16x8*)&lV[(j * 16 + lr) * 72 + lg * 8];
      bf16x8 vf1 = *(const bf16x8*)&lV[(j * 16 + lr) * 72 + 32 + lg * 8];
      acc[j] = __builtin_amdgcn_mfma_f32_16x16x32_bf16(pa0, vf0, acc[j], 0, 0, 0);
      acc[j] = __builtin_amdgcn_mfma_f32_16x16x32_bf16(pa1, vf1, acc[j], 0, 0, 0);
    }
  }

  int b = bh >> 4, hh = bh & 15;
#pragma unroll
  for (int r = 0; r < 4; ++r) {
    float inv = 1.0f / ls[r];
    int tok = b * 1024 + qt * 64 + w * 16 + lg * 4 + r;
#pragma unroll
    for (int j = 0; j < 4; ++j) {
      int col = hh * 64 + j * 16 + lr;
      ao[(size_t)tok * 1024 + col] = f2bf(acc[j][r] * inv);
    }
  }
}

extern "C" void kernel_launch(void* const* d_in, const int* in_sizes, int n_in,
                              void* d_out, int out_size, void* d_ws, size_t ws_size,
                              hipStream_t stream) {
  const float* query  = (const float*)d_in[0];
  const float* w_qkv  = (const float*)d_in[1];
  const float* b_qkv  = (const float*)d_in[2];
  const float* w_proj = (const float*)d_in[3];
  const float* b_proj = (const float*)d_in[4];
  float* out = (float*)d_out;
  char* ws = (char*)d_ws;

  short* qbf = (short*)(ws);                    // 16,777,216 B  (reused as ao)
  short* wT  = (short*)(ws + 16777216);         //  6,291,456 B
  short* wpT = (short*)(ws + 23068672);         //  2,097,152 B
  short* qb  = (short*)(ws + 25165824);         // 16,777,216 B
  short* kb  = (short*)(ws + 41943040);         // 16,777,216 B
  short* vb  = (short*)(ws + 58720256);         // 16,777,216 B
  short* vt  = (short*)(ws + 75497472);         // 16,777,216 B  (total 92,274,688)
  short* ao  = qbf;                             // qbf dead after QKV GEMM

  k_cvt<<<4096, 256, 0, stream>>>(query, qbf, 1048576);
  k_tcvt<<<dim3(48, 16), 256, 0, stream>>>(w_qkv, wT, 1024, 3072);
  k_tcvt<<<dim3(16, 16), 256, 0, stream>>>(w_proj, wpT, 1024, 1024);
  k_gemm<0><<<dim3(24, 64), 256, 0, stream>>>(qbf, wT, b_qkv, qb, kb, vb);
  k_vt<<<dim3(16, 128), 256, 0, stream>>>(vb, vt);
  k_attn<<<2048, 256, 0, stream>>>(qb, kb, vt, ao);
  k_gemm<1><<<dim3(8, 64), 256, 0, stream>>>(ao, wpT, b_proj, out, nullptr, nullptr);
}